// Round 6
// baseline (322.337 us; speedup 1.0000x reference)
//
#include <hip/hip_runtime.h>
#include <hip/hip_bf16.h>
#include <stdint.h>

// CausalSelfAttention  B=2 L=4096 D=768 H=12 Dh=64
// Dual-dtype inputs (fp32 reference or bf16-lowered), detected on device.
// Internals bf16 MFMA. ws: flag(64B) | q,k planes [bh][l][64] | vT plane
// [bh][d][L] | y/xbf overlay [8192][768] | WqkvT [2304][768] | WoT [768][768]
// Fragment-order LDS staging: tiles live in LDS as (frag,k-half) blocks of
// 64 lanes x 16B, staged by global_load_lds with per-lane global addresses,
// read back at uniform_base + lane*16 (conflict-free, swizzle-free).
#define BB 2
#define LL 4096
#define DD 768
#define HH 12
#define DH 64
#define MM (BB * LL)
#define NQKV (3 * DD)
#define KK 768
#define PLANE ((size_t)BB * HH * LL * DH)
#define SQSCALE 0.1803368801111204f   // 0.125 * log2(e)

typedef __attribute__((ext_vector_type(8))) short bf16x8;
typedef __attribute__((ext_vector_type(4))) float f32x4;

__device__ __forceinline__ float bf2f(uint16_t u) {
  union { uint32_t u; float f; } c; c.u = ((uint32_t)u) << 16; return c.f;
}
__device__ __forceinline__ uint16_t f2bf(float f) {
  union { float f; uint32_t u; } c; c.f = f;
  return (uint16_t)((c.u + 0x7FFFu + ((c.u >> 16) & 1u)) >> 16);
}
// packed 2xf32 -> 2xbf16 (v_cvt_pk_bf16_f32); a low 16, b high 16
__device__ __forceinline__ uint32_t cvt2(float a, float b) {
  __hip_bfloat162 h = __float22bfloat162_rn(make_float2(a, b));
  union { __hip_bfloat162 h; uint32_t u; } c; c.h = h; return c.u;
}

union H8 { uint16_t h[8]; uint32_t w[4]; uint4 v; };
union B8 { uint2 d[2]; bf16x8 v; };

template <bool F32>
__device__ __forceinline__ H8 load8(const void* p, size_t idx) {
  H8 r;
  if (F32) {
    const float* f = (const float*)p + idx;
    float4 a = *(const float4*)f;
    float4 b = *(const float4*)(f + 4);
    r.w[0] = cvt2(a.x, a.y); r.w[1] = cvt2(a.z, a.w);
    r.w[2] = cvt2(b.x, b.y); r.w[3] = cvt2(b.z, b.w);
  } else {
    r.v = *(const uint4*)((const uint16_t*)p + idx);
  }
  return r;
}

// async global->LDS, 16B per lane; lds ptr wave-uniform, global per-lane
__device__ __forceinline__ void g2l16(const uint16_t* g, uint16_t* l) {
  __builtin_amdgcn_global_load_lds((const __attribute__((address_space(1))) void*)g,
                                   (__attribute__((address_space(3))) void*)l,
                                   16, 0, 0);
}

// ---------------- dtype detection ------------------------------------------
__global__ void detect_k(const uint16_t* __restrict__ x, int* __restrict__ flag) {
  __shared__ int cnt;
  if (threadIdx.x == 0) cnt = 0;
  __syncthreads();
  int c = 0;
  for (int i = threadIdx.x; i < 4096; i += 256) {
    int e = (x[i] >> 7) & 0xFF;
    if (e == 0xFF || e > 133 || e < 100) c++;
  }
  atomicAdd(&cnt, c);
  __syncthreads();
  if (threadIdx.x == 0) *flag = (cnt > 512) ? 1 : 0;
}

// ---------------- merged prep: x->bf16, WqkvT, WoT -------------------------
__global__ __launch_bounds__(256) void prep_k(const void* __restrict__ x,
                                              uint16_t* __restrict__ xbf,
                                              const void* __restrict__ Wqkv,
                                              uint16_t* __restrict__ wqkvT,
                                              const void* __restrict__ Wo,
                                              uint16_t* __restrict__ woT,
                                              const int* __restrict__ flag) {
  __shared__ uint16_t Ts[64][65];
  const int fl = *flag;
  const int id = blockIdx.x;
  const int tid = threadIdx.x;
  if (id < 768) {
    size_t base = (size_t)id * 1024 + tid;
#pragma unroll
    for (int j = 0; j < 4; ++j) {
      size_t i = base + j * 256;
      H8 v = fl ? load8<true>(x, i * 8) : load8<false>(x, i * 8);
      *(uint4*)(xbf + i * 8) = v.v;
    }
    return;
  }
  const void* W;
  uint16_t* WT;
  int N, widx;
  if (id < 1200) { W = Wqkv; WT = wqkvT; N = NQKV; widx = id - 768; }
  else           { W = Wo;   WT = woT;   N = DD;   widx = id - 1200; }
  const int nb = N / 64;
  const int n0 = (widx % nb) * 64, k0 = (widx / nb) * 64;
#pragma unroll
  for (int j = 0; j < 16; ++j) {
    int idx = tid + j * 256;
    int r = idx >> 6, c = idx & 63;
    size_t gi = (size_t)(k0 + r) * N + n0 + c;
    float v = fl ? ((const float*)W)[gi] : bf2f(((const uint16_t*)W)[gi]);
    Ts[c][r] = f2bf(v);
  }
  __syncthreads();
#pragma unroll
  for (int j = 0; j < 16; ++j) {
    int idx = tid + j * 256;
    int n = idx >> 6, k = idx & 63;
    WT[(size_t)(n0 + n) * KK + k0 + k] = Ts[n][k];
  }
}

// ---------------- 128x128 GEMM core, BK=64, fragment-order staging ---------
// Af/Bf: 16 blocks of 512 halves each (1KB). Block ab = (wm*4+i)*2+h.
__device__ __forceinline__ void gemm128_core(const uint16_t* __restrict__ A,
                                             const uint16_t* __restrict__ BT,
                                             int m0, int n0,
                                             uint16_t* Af, uint16_t* Bf,
                                             f32x4 acc[4][4]) {
  const int tid = threadIdx.x, lane = tid & 63, w = tid >> 6;
  const int c16 = lane & 15, quad = lane >> 4;
  const int wm = w >> 1, wn = w & 1;
  // wave w stages A blocks w*4..w*4+3 and B blocks w*4..w*4+3
  const uint16_t* ga[4]; const uint16_t* gb[4];
  uint16_t* la[4]; uint16_t* lb[4];
#pragma unroll
  for (int j = 0; j < 4; ++j) {
    int ab = w * 4 + j;
    int bwm = ab >> 3, bi = (ab >> 1) & 3, bhh = ab & 1;
    int col = bhh * 32 + quad * 8;
    ga[j] = A + (size_t)(m0 + bwm * 64 + bi * 16 + c16) * KK + col;
    gb[j] = BT + (size_t)(n0 + bwm * 64 + bi * 16 + c16) * KK + col;
    la[j] = Af + ab * 512;
    lb[j] = Bf + ab * 512;
  }
  const int abase = wm * 8;   // (wm*4+i)*2+h = abase + i*2 + h
  const int bbase = wn * 8;
  for (int k0 = 0; k0 < KK; k0 += 64) {
#pragma unroll
    for (int j = 0; j < 4; ++j) {
      g2l16(ga[j], la[j]); g2l16(gb[j], lb[j]);
      ga[j] += 64; gb[j] += 64;
    }
    __syncthreads();
#pragma unroll
    for (int h = 0; h < 2; ++h) {
      bf16x8 a[4], b[4];
#pragma unroll
      for (int i = 0; i < 4; ++i)
        a[i] = *(const bf16x8*)(Af + (abase + i * 2 + h) * 512 + lane * 8);
#pragma unroll
      for (int f = 0; f < 4; ++f)
        b[f] = *(const bf16x8*)(Bf + (bbase + f * 2 + h) * 512 + lane * 8);
#pragma unroll
      for (int i = 0; i < 4; ++i)
#pragma unroll
        for (int f = 0; f < 4; ++f)
          acc[i][f] = __builtin_amdgcn_mfma_f32_16x16x32_bf16(a[i], b[f], acc[i][f], 0, 0, 0);
    }
    __syncthreads();
  }
}

// ---------------- kernel: QKV projection (writes q,k,vT planes) ------------
__global__ __launch_bounds__(256) void qkv128_k(const uint16_t* __restrict__ X,
                                                const uint16_t* __restrict__ WT,
                                                const void* __restrict__ bias,
                                                uint16_t* __restrict__ planes,
                                                const int* __restrict__ flag) {
  __shared__ __align__(16) uint16_t smem[16384];   // Af[0..8192) Bf[8192..); Ts overlay
  uint16_t* Af = smem;
  uint16_t* Bf = smem + 8192;
  const int fl = *flag;
  const int m0 = blockIdx.x * 128, n0 = blockIdx.y * 128;
  f32x4 acc[4][4];
#pragma unroll
  for (int i = 0; i < 4; ++i)
#pragma unroll
    for (int f = 0; f < 4; ++f) acc[i][f] = (f32x4){0.f, 0.f, 0.f, 0.f};
  gemm128_core(X, WT, m0, n0, Af, Bf, acc);

  const int tid = threadIdx.x, lane = tid & 63, w = tid >> 6;
  const int quad = lane >> 4, c16 = lane & 15;
  const int wm = w >> 1, wn = w & 1;
  const int which = (n0 >= 2 * DD) ? 2 : (n0 >= DD ? 1 : 0);

  if (which < 2) {
    uint16_t* dst = planes + (size_t)which * PLANE;
    const float sc = (which == 0) ? SQSCALE : 1.0f;
#pragma unroll
    for (int f = 0; f < 4; ++f) {
      int n = n0 + wn * 64 + f * 16 + c16;
      float bv = fl ? ((const float*)bias)[n] : bf2f(((const uint16_t*)bias)[n]);
      int rem = n - which * DD;
      int hh = rem >> 6, dd = rem & 63;
#pragma unroll
      for (int i = 0; i < 4; ++i) {
        uint32_t pa = cvt2((acc[i][f][0] + bv) * sc, (acc[i][f][1] + bv) * sc);
        uint32_t pb = cvt2((acc[i][f][2] + bv) * sc, (acc[i][f][3] + bv) * sc);
        int m = m0 + wm * 64 + i * 16 + quad * 4;
        int b = m >> 12, l = m & (LL - 1);
        uint16_t* base = dst + ((size_t)(b * HH + hh) * LL + l) * DH + dd;
        base[0 * DH] = (uint16_t)pa;
        base[1 * DH] = (uint16_t)(pa >> 16);
        base[2 * DH] = (uint16_t)pb;
        base[3 * DH] = (uint16_t)(pb >> 16);
      }
    }
  } else {
    uint16_t (*Ts)[136] = reinterpret_cast<uint16_t(*)[136]>(smem);  // 8704 halves
    uint16_t* vtp = planes + 2 * PLANE;
    const int l0 = m0 & (LL - 1), bb = m0 >> 12;
    for (int half = 0; half < 2; ++half) {
      __syncthreads();
      if (wn == half) {
#pragma unroll
        for (int f = 0; f < 4; ++f) {
          int n = n0 + half * 64 + f * 16 + c16;
          float bv = fl ? ((const float*)bias)[n] : bf2f(((const uint16_t*)bias)[n]);
#pragma unroll
          for (int i = 0; i < 4; ++i) {
            uint32_t pa = cvt2(acc[i][f][0] + bv, acc[i][f][1] + bv);
            uint32_t pb = cvt2(acc[i][f][2] + bv, acc[i][f][3] + bv);
            *(uint2*)(&Ts[f * 16 + c16][wm * 64 + i * 16 + quad * 4]) = make_uint2(pa, pb);
          }
        }
      }
      __syncthreads();
#pragma unroll
      for (int j = 0; j < 4; ++j) {
        int idx = tid + j * 256;
        int nl = idx >> 4, ch = idx & 15;
        int rem = n0 + half * 64 + nl - 2 * DD;
        int hh = rem >> 6, dd = rem & 63;
        uint4 val = *(const uint4*)(&Ts[nl][ch * 8]);
        *(uint4*)(vtp + ((size_t)(bb * HH + hh) * DH + dd) * LL + l0 + ch * 8) = val;
      }
    }
  }
}

// ---------------- kernel: flash attention (causal, paired q-tiles) ---------
// Fragment-order K/V staging via global_load_lds; S^T + no-max softmax.
__global__ __launch_bounds__(256) void attn_k(const uint16_t* __restrict__ planes,
                                              uint16_t* __restrict__ y) {
  __shared__ __align__(16) uint16_t Kf[2][4096];   // 8 blocks (f*2+h) x 512
  __shared__ __align__(16) uint16_t Vf[2][4096];   // 8 blocks (g*2+h) x 512
  __shared__ __align__(16) uint16_t Ps[4][1024];
  const int p = blockIdx.x;            // 0..31 -> q tiles {63-p, p}
  const int bh = blockIdx.y;           // 0..23
  const uint16_t* qb = planes + (size_t)bh * LL * DH;
  const uint16_t* kb = qb + PLANE;
  const uint16_t* vtb = planes + 2 * PLANE + (size_t)bh * DH * LL;  // [d][L]
  const int tid = threadIdx.x, lane = tid & 63, wv = tid >> 6;
  const int quad = lane >> 4, c16 = lane & 15;
  uint16_t* Psb = Ps[wv];
  const int b = bh / HH, hh = bh - b * HH;
  const int pwbase = c16 * 64;
  const int prd0 = pwbase + (((2 * quad) ^ c16) << 2);
  const int prd1 = pwbase + (((2 * quad + 1) ^ c16) << 2);
  const int prd2 = pwbase + (((8 + 2 * quad) ^ c16) << 2);
  const int prd3 = pwbase + (((8 + 2 * quad + 1) ^ c16) << 2);
  // wave wv stages K blocks (f=wv,h=0/1) and V blocks (g=wv,h=0/1)
  uint16_t* lk0 = nullptr;  // set per buffer below

  for (int pass = 0; pass < 2; ++pass) {
    const int qi = pass ? p : 63 - p;
    const int q0 = qi * 64;
    // staging pointers for tile 0
    const uint16_t* gk = kb + (size_t)(wv * 16 + c16) * DH + quad * 8;
    const uint16_t* gv = vtb + (size_t)(wv * 16 + c16) * LL + quad * 8;
    // prologue: stage tile 0 into buf 0
    g2l16(gk,      Kf[0] + (wv * 2 + 0) * 512);
    g2l16(gk + 32, Kf[0] + (wv * 2 + 1) * 512);
    g2l16(gv,      Vf[0] + (wv * 2 + 0) * 512);
    g2l16(gv + 32, Vf[0] + (wv * 2 + 1) * 512);

    const size_t qoff = (size_t)(q0 + wv * 16 + c16) * DH;
    bf16x8 qf0 = *(const bf16x8*)(qb + qoff + quad * 8);
    bf16x8 qf1 = *(const bf16x8*)(qb + qoff + 32 + quad * 8);

    f32x4 o[4];
#pragma unroll
    for (int g = 0; g < 4; ++g) o[g] = (f32x4){0.f, 0.f, 0.f, 0.f};
    float l_i = 0.f;

    for (int t = 0; t <= qi; ++t) {
      __syncthreads();                 // buf[t&1] staged (vmcnt drained); t-1 reads done
      if (t < qi) {
        gk += 64 * DH;                 // next 64 keys
        gv += 64;
        uint16_t* kn = Kf[(t + 1) & 1];
        uint16_t* vn = Vf[(t + 1) & 1];
        g2l16(gk,      kn + (wv * 2 + 0) * 512);
        g2l16(gk + 32, kn + (wv * 2 + 1) * 512);
        g2l16(gv,      vn + (wv * 2 + 0) * 512);
        g2l16(gv + 32, vn + (wv * 2 + 1) * 512);
      }
      const uint16_t* kd = Kf[t & 1];
      const uint16_t* vd = Vf[t & 1];

      // S^T = K Q^T: D[key = f*16 + quad*4 + r][q = c16]
      f32x4 s[4];
#pragma unroll
      for (int f = 0; f < 4; ++f) {
        bf16x8 k0f = *(const bf16x8*)(kd + (f * 2 + 0) * 512 + lane * 8);
        bf16x8 k1f = *(const bf16x8*)(kd + (f * 2 + 1) * 512 + lane * 8);
        f32x4 z = {0.f, 0.f, 0.f, 0.f};
        z = __builtin_amdgcn_mfma_f32_16x16x32_bf16(k0f, qf0, z, 0, 0, 0);
        z = __builtin_amdgcn_mfma_f32_16x16x32_bf16(k1f, qf1, z, 0, 0, 0);
        s[f] = z;
      }
      const int qg = q0 + wv * 16 + c16;
      if (t == qi) {                   // diagonal tile: causal mask
#pragma unroll
        for (int f = 0; f < 4; ++f) {
          int key0 = t * 64 + f * 16 + quad * 4;
#pragma unroll
          for (int r = 0; r < 4; ++r) {
            float pv = exp2f(s[f][r]);
            pv = (key0 + r <= qg) ? pv : 0.f;
            s[f][r] = pv;
            l_i += pv;
          }
        }
      } else {
#pragma unroll
        for (int f = 0; f < 4; ++f)
#pragma unroll
          for (int r = 0; r < 4; ++r) {
            float pv = exp2f(s[f][r]);
            s[f][r] = pv;
            l_i += pv;
          }
      }
      // P: C-layout -> wave-private LDS -> A-layout (4 packed b64 each way)
#pragma unroll
      for (int f = 0; f < 4; ++f) {
        uint32_t w0 = cvt2(s[f][0], s[f][1]);
        uint32_t w1 = cvt2(s[f][2], s[f][3]);
        *(uint2*)(Psb + pwbase + (((f * 4 + quad) ^ c16) << 2)) = make_uint2(w0, w1);
      }
      __asm__ __volatile__("s_waitcnt lgkmcnt(0)" ::: "memory");
      B8 p0, p1;
      p0.d[0] = *(const uint2*)(Psb + prd0);
      p0.d[1] = *(const uint2*)(Psb + prd1);
      p1.d[0] = *(const uint2*)(Psb + prd2);
      p1.d[1] = *(const uint2*)(Psb + prd3);
#pragma unroll
      for (int g = 0; g < 4; ++g) {
        bf16x8 v0 = *(const bf16x8*)(vd + (g * 2 + 0) * 512 + lane * 8);
        bf16x8 v1 = *(const bf16x8*)(vd + (g * 2 + 1) * 512 + lane * 8);
        o[g] = __builtin_amdgcn_mfma_f32_16x16x32_bf16(p0.v, v0, o[g], 0, 0, 0);
        o[g] = __builtin_amdgcn_mfma_f32_16x16x32_bf16(p1.v, v1, o[g], 0, 0, 0);
      }
    }

    l_i += __shfl_xor(l_i, 16);
    l_i += __shfl_xor(l_i, 32);
    float inv[4];
#pragma unroll
    for (int r = 0; r < 4; ++r)
      inv[r] = 1.f / __shfl(l_i, (quad << 4) + quad * 4 + r);
#pragma unroll
    for (int g = 0; g < 4; ++g) {
      uint32_t pa = cvt2(o[g][0] * inv[0], o[g][1] * inv[1]);
      uint32_t pb = cvt2(o[g][2] * inv[2], o[g][3] * inv[3]);
      int l = q0 + wv * 16 + quad * 4;
      uint16_t* base = y + ((size_t)(b * LL + l)) * DD + hh * DH + g * 16 + c16;
      base[0 * DD] = (uint16_t)pa;
      base[1 * DD] = (uint16_t)(pa >> 16);
      base[2 * DD] = (uint16_t)pb;
      base[3 * DD] = (uint16_t)(pb >> 16);
    }
    __syncthreads();   // protect K/V buffers before next pass restages buf0
  }
  (void)lk0;
}

// ---------------- kernel: output projection (128m x 64n tiles) -------------
__global__ __launch_bounds__(256) void out64_k(const uint16_t* __restrict__ Y,
                                               const uint16_t* __restrict__ WT,
                                               const void* __restrict__ bias,
                                               void* __restrict__ out,
                                               const int* __restrict__ flag) {
  __shared__ __align__(16) uint16_t Af[16 * 512];  // blocks (w*2+i)*2+h
  __shared__ __align__(16) uint16_t Bf[8 * 512];   // blocks f*2+h
  const int fl = *flag;
  const int m0 = blockIdx.x * 128, n0 = blockIdx.y * 64;
  const int tid = threadIdx.x, lane = tid & 63, w = tid >> 6;
  const int c16 = lane & 15, quad = lane >> 4;
  f32x4 acc[2][4];
#pragma unroll
  for (int i = 0; i < 2; ++i)
#pragma unroll
    for (int f = 0; f < 4; ++f) acc[i][f] = (f32x4){0.f, 0.f, 0.f, 0.f};
  // staging: wave w: A blocks (bw=w, i 0..1, h 0..1); B blocks (f=w, h 0..1)
  const uint16_t* ga[4]; uint16_t* la[4];
#pragma unroll
  for (int j = 0; j < 4; ++j) {
    int i = j >> 1, h = j & 1;
    ga[j] = Y + (size_t)(m0 + w * 32 + i * 16 + c16) * KK + h * 32 + quad * 8;
    la[j] = Af + ((w * 2 + i) * 2 + h) * 512;
  }
  const uint16_t* gbp[2]; uint16_t* lbp[2];
#pragma unroll
  for (int h = 0; h < 2; ++h) {
    gbp[h] = WT + (size_t)(n0 + w * 16 + c16) * KK + h * 32 + quad * 8;
    lbp[h] = Bf + (w * 2 + h) * 512;
  }
  for (int k0 = 0; k0 < KK; k0 += 64) {
#pragma unroll
    for (int j = 0; j < 4; ++j) { g2l16(ga[j], la[j]); ga[j] += 64; }
#pragma unroll
    for (int h = 0; h < 2; ++h) { g2l16(gbp[h], lbp[h]); gbp[h] += 64; }
    __syncthreads();
#pragma unroll
    for (int h = 0; h < 2; ++h) {
      bf16x8 a[2], bfr[4];
#pragma unroll
      for (int i = 0; i < 2; ++i)
        a[i] = *(const bf16x8*)(Af + ((w * 2 + i) * 2 + h) * 512 + lane * 8);
#pragma unroll
      for (int f = 0; f < 4; ++f)
        bfr[f] = *(const bf16x8*)(Bf + (f * 2 + h) * 512 + lane * 8);
#pragma unroll
      for (int i = 0; i < 2; ++i)
#pragma unroll
        for (int f = 0; f < 4; ++f)
          acc[i][f] = __builtin_amdgcn_mfma_f32_16x16x32_bf16(a[i], bfr[f], acc[i][f], 0, 0, 0);
    }
    __syncthreads();
  }
#pragma unroll
  for (int f = 0; f < 4; ++f) {
    int n = n0 + f * 16 + c16;
    float bv = fl ? ((const float*)bias)[n] : bf2f(((const uint16_t*)bias)[n]);
#pragma unroll
    for (int i = 0; i < 2; ++i) {
      int m = m0 + w * 32 + i * 16 + quad * 4;
      if (fl) {
        float* base = (float*)out + (size_t)m * DD + n;
#pragma unroll
        for (int r = 0; r < 4; ++r) base[r * DD] = acc[i][f][r] + bv;
      } else {
        uint32_t pa = cvt2(acc[i][f][0] + bv, acc[i][f][1] + bv);
        uint32_t pb = cvt2(acc[i][f][2] + bv, acc[i][f][3] + bv);
        uint16_t* base = (uint16_t*)out + (size_t)m * DD + n;
        base[0 * DD] = (uint16_t)pa;
        base[1 * DD] = (uint16_t)(pa >> 16);
        base[2 * DD] = (uint16_t)pb;
        base[3 * DD] = (uint16_t)(pb >> 16);
      }
    }
  }
}

extern "C" void kernel_launch(void* const* d_in, const int* in_sizes, int n_in,
                              void* d_out, int out_size, void* d_ws, size_t ws_size,
                              hipStream_t stream) {
  const void* x    = d_in[0];
  const void* Wqkv = d_in[1];
  const void* bqkv = d_in[2];
  const void* Wo   = d_in[3];
  const void* bo   = d_in[4];
  int* flagp = (int*)d_ws;
  uint16_t* planes = (uint16_t*)((char*)d_ws + 64);
  uint16_t* y_ws   = planes + 3 * PLANE;
  uint16_t* wqkvT  = y_ws + (size_t)MM * DD;
  uint16_t* woT    = wqkvT + (size_t)NQKV * KK;
  uint16_t* xbf    = y_ws;   // overlay: consumed before attn writes y

  detect_k<<<1, 256, 0, stream>>>((const uint16_t*)x, flagp);
  prep_k<<<1344, 256, 0, stream>>>(x, xbf, Wqkv, wqkvT, Wo, woT, flagp);
  qkv128_k<<<dim3(MM / 128, NQKV / 128), 256, 0, stream>>>(xbf, wqkvT, bqkv, planes, flagp);
  attn_k<<<dim3(32, BB * HH), 256, 0, stream>>>(planes, y_ws);
  out64_k<<<dim3(MM / 128, DD / 64), 256, 0, stream>>>(y_ws, woT, bo, d_out, flagp);
}

// Round 7
// 269.279 us; speedup vs baseline: 1.1970x; 1.1970x over previous
//
#include <hip/hip_runtime.h>
#include <hip/hip_bf16.h>
#include <stdint.h>

// CausalSelfAttention  B=2 L=4096 D=768 H=12 Dh=64
// Dual-dtype inputs (fp32 reference or bf16-lowered), detected on device.
// Internals bf16 MFMA. ws: flag(64B) | q,k planes [bh][l][64] | vT plane
// [bh][d][L] | y/xbf overlay [8192][768] | WqkvT [2304][768] | WoT [768][768]
// R7 = R5 structure (g2l16 only with coalesced footprints) + Ts-overlay in
// qkv epilogue (LDS 33->17KB) + out proj retiled 128x64 (3 blocks/CU).
#define BB 2
#define LL 4096
#define DD 768
#define HH 12
#define DH 64
#define MM (BB * LL)
#define NQKV (3 * DD)
#define KK 768
#define PLANE ((size_t)BB * HH * LL * DH)
#define SQSCALE 0.1803368801111204f   // 0.125 * log2(e)

typedef __attribute__((ext_vector_type(8))) short bf16x8;
typedef __attribute__((ext_vector_type(4))) float f32x4;

__device__ __forceinline__ float bf2f(uint16_t u) {
  union { uint32_t u; float f; } c; c.u = ((uint32_t)u) << 16; return c.f;
}
__device__ __forceinline__ uint16_t f2bf(float f) {
  union { float f; uint32_t u; } c; c.f = f;
  return (uint16_t)((c.u + 0x7FFFu + ((c.u >> 16) & 1u)) >> 16);
}
// packed 2xf32 -> 2xbf16 (v_cvt_pk_bf16_f32); a low 16, b high 16
__device__ __forceinline__ uint32_t cvt2(float a, float b) {
  __hip_bfloat162 h = __float22bfloat162_rn(make_float2(a, b));
  union { __hip_bfloat162 h; uint32_t u; } c; c.h = h; return c.u;
}

union H8 { uint16_t h[8]; uint32_t w[4]; uint4 v; };
union B8 { uint2 d[2]; bf16x8 v; };

template <bool F32>
__device__ __forceinline__ H8 load8(const void* p, size_t idx) {
  H8 r;
  if (F32) {
    const float* f = (const float*)p + idx;
    float4 a = *(const float4*)f;
    float4 b = *(const float4*)(f + 4);
    r.w[0] = cvt2(a.x, a.y); r.w[1] = cvt2(a.z, a.w);
    r.w[2] = cvt2(b.x, b.y); r.w[3] = cvt2(b.z, b.w);
  } else {
    r.v = *(const uint4*)((const uint16_t*)p + idx);
  }
  return r;
}

// async global->LDS, 16B per lane; lds ptr wave-uniform
__device__ __forceinline__ void g2l16(const uint16_t* g, uint16_t* l) {
  __builtin_amdgcn_global_load_lds((const __attribute__((address_space(1))) void*)g,
                                   (__attribute__((address_space(3))) void*)l,
                                   16, 0, 0);
}

// ---------------- dtype detection ------------------------------------------
__global__ void detect_k(const uint16_t* __restrict__ x, int* __restrict__ flag) {
  __shared__ int cnt;
  if (threadIdx.x == 0) cnt = 0;
  __syncthreads();
  int c = 0;
  for (int i = threadIdx.x; i < 4096; i += 256) {
    int e = (x[i] >> 7) & 0xFF;
    if (e == 0xFF || e > 133 || e < 100) c++;
  }
  atomicAdd(&cnt, c);
  __syncthreads();
  if (threadIdx.x == 0) *flag = (cnt > 512) ? 1 : 0;
}

// ---------------- merged prep: x->bf16, WqkvT, WoT -------------------------
__global__ __launch_bounds__(256) void prep_k(const void* __restrict__ x,
                                              uint16_t* __restrict__ xbf,
                                              const void* __restrict__ Wqkv,
                                              uint16_t* __restrict__ wqkvT,
                                              const void* __restrict__ Wo,
                                              uint16_t* __restrict__ woT,
                                              const int* __restrict__ flag) {
  __shared__ uint16_t Ts[64][65];
  const int fl = *flag;
  const int id = blockIdx.x;
  const int tid = threadIdx.x;
  if (id < 768) {
    size_t base = (size_t)id * 1024 + tid;
#pragma unroll
    for (int j = 0; j < 4; ++j) {
      size_t i = base + j * 256;
      H8 v = fl ? load8<true>(x, i * 8) : load8<false>(x, i * 8);
      *(uint4*)(xbf + i * 8) = v.v;
    }
    return;
  }
  const void* W;
  uint16_t* WT;
  int N, widx;
  if (id < 1200) { W = Wqkv; WT = wqkvT; N = NQKV; widx = id - 768; }
  else           { W = Wo;   WT = woT;   N = DD;   widx = id - 1200; }
  const int nb = N / 64;
  const int n0 = (widx % nb) * 64, k0 = (widx / nb) * 64;
#pragma unroll
  for (int j = 0; j < 16; ++j) {
    int idx = tid + j * 256;
    int r = idx >> 6, c = idx & 63;
    size_t gi = (size_t)(k0 + r) * N + n0 + c;
    float v = fl ? ((const float*)W)[gi] : bf2f(((const uint16_t*)W)[gi]);
    Ts[c][r] = f2bf(v);
  }
  __syncthreads();
#pragma unroll
  for (int j = 0; j < 16; ++j) {
    int idx = tid + j * 256;
    int n = idx >> 6, k = idx & 63;
    WT[(size_t)(n0 + n) * KK + k0 + k] = Ts[n][k];
  }
}

// ---------------- 128x128 GEMM core (K=768, BK=32, g2l16) ------------------
// As/Bs: [128][32] halves, chunk-swizzled with g(row) = (row>>1)&3.
__device__ __forceinline__ void gemm128_core(const uint16_t* __restrict__ A,
                                             const uint16_t* __restrict__ BT,
                                             int m0, int n0,
                                             uint16_t* As, uint16_t* Bs,
                                             f32x4 acc[4][4]) {
  const int tid = threadIdx.x, lane = tid & 63, w = tid >> 6;
  const int quad = lane >> 4, c16 = lane & 15;
  const int wm = w >> 1, wn = w & 1;
  const int srow = lane >> 2, schunk = lane & 3;
  const int rsw = (c16 >> 1) & 3;
  for (int k0 = 0; k0 < KK; k0 += 32) {
#pragma unroll
    for (int i = 0; i < 2; ++i) {
      int row = w * 32 + i * 16 + srow;
      int gch = schunk ^ ((row >> 1) & 3);
      g2l16(A + (size_t)(m0 + row) * KK + k0 + gch * 8, As + (w * 32 + i * 16) * 32);
      g2l16(BT + (size_t)(n0 + row) * KK + k0 + gch * 8, Bs + (w * 32 + i * 16) * 32);
    }
    __syncthreads();
    bf16x8 a[4], b[4];
#pragma unroll
    for (int i = 0; i < 4; ++i) {
      a[i] = *(const bf16x8*)(As + (wm * 64 + i * 16 + c16) * 32 + ((quad ^ rsw) * 8));
      b[i] = *(const bf16x8*)(Bs + (wn * 64 + i * 16 + c16) * 32 + ((quad ^ rsw) * 8));
    }
#pragma unroll
    for (int i = 0; i < 4; ++i)
#pragma unroll
      for (int f = 0; f < 4; ++f)
        acc[i][f] = __builtin_amdgcn_mfma_f32_16x16x32_bf16(a[i], b[f], acc[i][f], 0, 0, 0);
    __syncthreads();
  }
}

// ---------------- kernel: QKV projection (writes q,k,vT planes) ------------
// LDS: As/Bs (16KB) with Ts (17.4KB) OVERLAID (epilogue-only) -> 17.4KB total
__global__ __launch_bounds__(256) void qkv128_k(const uint16_t* __restrict__ X,
                                                const uint16_t* __restrict__ WT,
                                                const void* __restrict__ bias,
                                                uint16_t* __restrict__ planes,
                                                const int* __restrict__ flag) {
  __shared__ __align__(16) uint16_t smem[8704];   // max(As+Bs=8192, Ts=8704)
  uint16_t* As = smem;
  uint16_t* Bs = smem + 4096;
  const int fl = *flag;
  const int m0 = blockIdx.x * 128, n0 = blockIdx.y * 128;
  f32x4 acc[4][4];
#pragma unroll
  for (int i = 0; i < 4; ++i)
#pragma unroll
    for (int f = 0; f < 4; ++f) acc[i][f] = (f32x4){0.f, 0.f, 0.f, 0.f};
  gemm128_core(X, WT, m0, n0, As, Bs, acc);

  const int tid = threadIdx.x, lane = tid & 63, w = tid >> 6;
  const int quad = lane >> 4, c16 = lane & 15;
  const int wm = w >> 1, wn = w & 1;
  const int which = (n0 >= 2 * DD) ? 2 : (n0 >= DD ? 1 : 0);

  if (which < 2) {
    uint16_t* dst = planes + (size_t)which * PLANE;
    const float sc = (which == 0) ? SQSCALE : 1.0f;
#pragma unroll
    for (int f = 0; f < 4; ++f) {
      int n = n0 + wn * 64 + f * 16 + c16;
      float bv = fl ? ((const float*)bias)[n] : bf2f(((const uint16_t*)bias)[n]);
      int rem = n - which * DD;
      int hh = rem >> 6, dd = rem & 63;
#pragma unroll
      for (int i = 0; i < 4; ++i) {
        uint32_t pa = cvt2((acc[i][f][0] + bv) * sc, (acc[i][f][1] + bv) * sc);
        uint32_t pb = cvt2((acc[i][f][2] + bv) * sc, (acc[i][f][3] + bv) * sc);
        int m = m0 + wm * 64 + i * 16 + quad * 4;
        int b = m >> 12, l = m & (LL - 1);
        uint16_t* base = dst + ((size_t)(b * HH + hh) * LL + l) * DH + dd;
        base[0 * DH] = (uint16_t)pa;
        base[1 * DH] = (uint16_t)(pa >> 16);
        base[2 * DH] = (uint16_t)pb;
        base[3 * DH] = (uint16_t)(pb >> 16);
      }
    }
  } else {
    uint16_t (*Ts)[136] = reinterpret_cast<uint16_t(*)[136]>(smem);  // overlay
    uint16_t* vtp = planes + 2 * PLANE;
    const int l0 = m0 & (LL - 1), bb = m0 >> 12;
    for (int half = 0; half < 2; ++half) {
      __syncthreads();   // As/Bs reads done (GEMM over) / prev half drained
      if (wn == half) {
#pragma unroll
        for (int f = 0; f < 4; ++f) {
          int n = n0 + half * 64 + f * 16 + c16;
          float bv = fl ? ((const float*)bias)[n] : bf2f(((const uint16_t*)bias)[n]);
#pragma unroll
          for (int i = 0; i < 4; ++i) {
            uint32_t pa = cvt2(acc[i][f][0] + bv, acc[i][f][1] + bv);
            uint32_t pb = cvt2(acc[i][f][2] + bv, acc[i][f][3] + bv);
            *(uint2*)(&Ts[f * 16 + c16][wm * 64 + i * 16 + quad * 4]) = make_uint2(pa, pb);
          }
        }
      }
      __syncthreads();
#pragma unroll
      for (int j = 0; j < 4; ++j) {
        int idx = tid + j * 256;
        int nl = idx >> 4, ch = idx & 15;
        int rem = n0 + half * 64 + nl - 2 * DD;
        int hh = rem >> 6, dd = rem & 63;
        uint4 val = *(const uint4*)(&Ts[nl][ch * 8]);
        *(uint4*)(vtp + ((size_t)(bb * HH + hh) * DH + dd) * LL + l0 + ch * 8) = val;
      }
    }
  }
}

// ---------------- kernel: flash attention (R5-exact) -----------------------
// S^T orientation + no-max softmax + packed P transpose + LDS dbuf.
__global__ __launch_bounds__(256) void attn_k(const uint16_t* __restrict__ planes,
                                              uint16_t* __restrict__ y) {
  __shared__ __align__(16) uint16_t Ks[2][64 * 64];
  __shared__ __align__(16) uint16_t Vt[2][64 * 64];
  __shared__ __align__(16) uint16_t Ps[4][16 * 64];
  const int p = blockIdx.x;            // 0..31 -> q tiles {63-p, p}
  const int bh = blockIdx.y;           // 0..23
  const uint16_t* qb = planes + (size_t)bh * LL * DH;
  const uint16_t* kb = qb + PLANE;
  const uint16_t* vtb = planes + 2 * PLANE + (size_t)bh * DH * LL;  // [d][L]
  const int tid = threadIdx.x, lane = tid & 63, wv = tid >> 6;
  const int quad = lane >> 4, c16 = lane & 15;
  const int r0 = tid >> 3, c0 = tid & 7;
  const int sw0 = r0 & 7;
  const int swf = c16 & 7;
  uint16_t* Psb = Ps[wv];
  const int b = bh / HH, hh = bh - b * HH;
  const int pwbase = c16 * 64;
  const int prd0 = pwbase + (((2 * quad) ^ c16) << 2);
  const int prd1 = pwbase + (((2 * quad + 1) ^ c16) << 2);
  const int prd2 = pwbase + (((8 + 2 * quad) ^ c16) << 2);
  const int prd3 = pwbase + (((8 + 2 * quad + 1) ^ c16) << 2);

  for (int pass = 0; pass < 2; ++pass) {
    const int qi = pass ? p : 63 - p;
    const int q0 = qi * 64;
    const size_t qoff = (size_t)(q0 + wv * 16 + c16) * DH;
    bf16x8 qf0 = *(const bf16x8*)(qb + qoff + quad * 8);
    bf16x8 qf1 = *(const bf16x8*)(qb + qoff + 32 + quad * 8);

    f32x4 o[4];
#pragma unroll
    for (int g = 0; g < 4; ++g) o[g] = (f32x4){0.f, 0.f, 0.f, 0.f};
    float l_i = 0.f;

    uint4 kr0 = *(const uint4*)(kb + (size_t)r0 * DH + c0 * 8);
    uint4 kr1 = *(const uint4*)(kb + (size_t)(r0 + 32) * DH + c0 * 8);
    uint4 vr0 = *(const uint4*)(vtb + (size_t)r0 * LL + c0 * 8);
    uint4 vr1 = *(const uint4*)(vtb + (size_t)(r0 + 32) * LL + c0 * 8);

    for (int t = 0; t <= qi; ++t) {
      uint16_t* kd = Ks[t & 1];
      uint16_t* vd = Vt[t & 1];
      *(uint4*)(kd + r0 * 64 + (c0 ^ sw0) * 8) = kr0;
      *(uint4*)(kd + (r0 + 32) * 64 + (c0 ^ sw0) * 8) = kr1;
      *(uint4*)(vd + r0 * 64 + (c0 ^ sw0) * 8) = vr0;
      *(uint4*)(vd + (r0 + 32) * 64 + (c0 ^ sw0) * 8) = vr1;
      if (t < qi) {
        int t64 = (t + 1) * 64;
        kr0 = *(const uint4*)(kb + (size_t)(t64 + r0) * DH + c0 * 8);
        kr1 = *(const uint4*)(kb + (size_t)(t64 + r0 + 32) * DH + c0 * 8);
        vr0 = *(const uint4*)(vtb + (size_t)r0 * LL + t64 + c0 * 8);
        vr1 = *(const uint4*)(vtb + (size_t)(r0 + 32) * LL + t64 + c0 * 8);
      }
      __syncthreads();

      // S^T = K Q^T: D[key=quad*4+r (+16f)][q=c16]
      f32x4 s[4];
#pragma unroll
      for (int f = 0; f < 4; ++f) {
        const uint16_t* krow = kd + (f * 16 + c16) * 64;
        bf16x8 k0f = *(const bf16x8*)(krow + ((quad ^ swf) * 8));
        bf16x8 k1f = *(const bf16x8*)(krow + (((quad + 4) ^ swf) * 8));
        f32x4 z = {0.f, 0.f, 0.f, 0.f};
        z = __builtin_amdgcn_mfma_f32_16x16x32_bf16(k0f, qf0, z, 0, 0, 0);
        z = __builtin_amdgcn_mfma_f32_16x16x32_bf16(k1f, qf1, z, 0, 0, 0);
        s[f] = z;
      }
      const int qg = q0 + wv * 16 + c16;
      if (t == qi) {
#pragma unroll
        for (int f = 0; f < 4; ++f) {
          int key0 = t * 64 + f * 16 + quad * 4;
#pragma unroll
          for (int r = 0; r < 4; ++r) {
            float pv = exp2f(s[f][r]);
            pv = (key0 + r <= qg) ? pv : 0.f;
            s[f][r] = pv;
            l_i += pv;
          }
        }
      } else {
#pragma unroll
        for (int f = 0; f < 4; ++f)
#pragma unroll
          for (int r = 0; r < 4; ++r) {
            float pv = exp2f(s[f][r]);
            s[f][r] = pv;
            l_i += pv;
          }
      }
#pragma unroll
      for (int f = 0; f < 4; ++f) {
        uint32_t w0 = cvt2(s[f][0], s[f][1]);
        uint32_t w1 = cvt2(s[f][2], s[f][3]);
        *(uint2*)(Psb + pwbase + (((f * 4 + quad) ^ c16) << 2)) = make_uint2(w0, w1);
      }
      __asm__ __volatile__("s_waitcnt lgkmcnt(0)" ::: "memory");
      B8 p0, p1;
      p0.d[0] = *(const uint2*)(Psb + prd0);
      p0.d[1] = *(const uint2*)(Psb + prd1);
      p1.d[0] = *(const uint2*)(Psb + prd2);
      p1.d[1] = *(const uint2*)(Psb + prd3);
#pragma unroll
      for (int g = 0; g < 4; ++g) {
        const uint16_t* vrow = vd + (g * 16 + c16) * 64;
        bf16x8 v0 = *(const bf16x8*)(vrow + ((quad ^ swf) * 8));
        bf16x8 v1 = *(const bf16x8*)(vrow + (((quad + 4) ^ swf) * 8));
        o[g] = __builtin_amdgcn_mfma_f32_16x16x32_bf16(p0.v, v0, o[g], 0, 0, 0);
        o[g] = __builtin_amdgcn_mfma_f32_16x16x32_bf16(p1.v, v1, o[g], 0, 0, 0);
      }
    }

    l_i += __shfl_xor(l_i, 16);
    l_i += __shfl_xor(l_i, 32);
    float inv[4];
#pragma unroll
    for (int r = 0; r < 4; ++r)
      inv[r] = 1.f / __shfl(l_i, (quad << 4) + quad * 4 + r);
#pragma unroll
    for (int g = 0; g < 4; ++g) {
      uint32_t pa = cvt2(o[g][0] * inv[0], o[g][1] * inv[1]);
      uint32_t pb = cvt2(o[g][2] * inv[2], o[g][3] * inv[3]);
      int l = q0 + wv * 16 + quad * 4;
      uint16_t* base = y + ((size_t)(b * LL + l)) * DD + hh * DH + g * 16 + c16;
      base[0 * DD] = (uint16_t)pa;
      base[1 * DD] = (uint16_t)(pa >> 16);
      base[2 * DD] = (uint16_t)pb;
      base[3 * DD] = (uint16_t)(pb >> 16);
    }
    __syncthreads();   // protect K/V buffers before next pass
  }
}

// ---------------- kernel: output projection (128m x 64n, BK=32) ------------
__global__ __launch_bounds__(256) void out64_k(const uint16_t* __restrict__ Y,
                                               const uint16_t* __restrict__ WT,
                                               const void* __restrict__ bias,
                                               void* __restrict__ out,
                                               const int* __restrict__ flag) {
  __shared__ __align__(16) uint16_t As[128 * 32];  // [row][32] swizzled
  __shared__ __align__(16) uint16_t Bs[64 * 32];
  const int fl = *flag;
  const int m0 = blockIdx.x * 128, n0 = blockIdx.y * 64;
  const int tid = threadIdx.x, lane = tid & 63, w = tid >> 6;
  const int quad = lane >> 4, c16 = lane & 15;
  const int srow = lane >> 2, schunk = lane & 3;
  const int rsw = (c16 >> 1) & 3;
  f32x4 acc[2][4];
#pragma unroll
  for (int i = 0; i < 2; ++i)
#pragma unroll
    for (int f = 0; f < 4; ++f) acc[i][f] = (f32x4){0.f, 0.f, 0.f, 0.f};
  for (int k0 = 0; k0 < KK; k0 += 32) {
    // A: 8 instrs (16 rows each), wave w does rows w*32..w*32+31
#pragma unroll
    for (int i = 0; i < 2; ++i) {
      int row = w * 32 + i * 16 + srow;
      int gch = schunk ^ ((row >> 1) & 3);
      g2l16(Y + (size_t)(m0 + row) * KK + k0 + gch * 8, As + (w * 32 + i * 16) * 32);
    }
    // B: 4 instrs, wave w does rows w*16..w*16+15
    {
      int row = w * 16 + srow;
      int gch = schunk ^ ((row >> 1) & 3);
      g2l16(WT + (size_t)(n0 + row) * KK + k0 + gch * 8, Bs + (w * 16) * 32);
    }
    __syncthreads();
    bf16x8 a[2], bfr[4];
#pragma unroll
    for (int i = 0; i < 2; ++i)
      a[i] = *(const bf16x8*)(As + (w * 32 + i * 16 + c16) * 32 + ((quad ^ rsw) * 8));
#pragma unroll
    for (int f = 0; f < 4; ++f)
      bfr[f] = *(const bf16x8*)(Bs + (f * 16 + c16) * 32 + ((quad ^ rsw) * 8));
#pragma unroll
    for (int i = 0; i < 2; ++i)
#pragma unroll
      for (int f = 0; f < 4; ++f)
        acc[i][f] = __builtin_amdgcn_mfma_f32_16x16x32_bf16(a[i], bfr[f], acc[i][f], 0, 0, 0);
    __syncthreads();
  }
#pragma unroll
  for (int f = 0; f < 4; ++f) {
    int n = n0 + f * 16 + c16;
    float bv = fl ? ((const float*)bias)[n] : bf2f(((const uint16_t*)bias)[n]);
#pragma unroll
    for (int i = 0; i < 2; ++i) {
      int m = m0 + w * 32 + i * 16 + quad * 4;
      if (fl) {
        float* base = (float*)out + (size_t)m * DD + n;
#pragma unroll
        for (int r = 0; r < 4; ++r) base[r * DD] = acc[i][f][r] + bv;
      } else {
        uint32_t pa = cvt2(acc[i][f][0] + bv, acc[i][f][1] + bv);
        uint32_t pb = cvt2(acc[i][f][2] + bv, acc[i][f][3] + bv);
        uint16_t* base = (uint16_t*)out + (size_t)m * DD + n;
        base[0 * DD] = (uint16_t)pa;
        base[1 * DD] = (uint16_t)(pa >> 16);
        base[2 * DD] = (uint16_t)pb;
        base[3 * DD] = (uint16_t)(pb >> 16);
      }
    }
  }
}

extern "C" void kernel_launch(void* const* d_in, const int* in_sizes, int n_in,
                              void* d_out, int out_size, void* d_ws, size_t ws_size,
                              hipStream_t stream) {
  const void* x    = d_in[0];
  const void* Wqkv = d_in[1];
  const void* bqkv = d_in[2];
  const void* Wo   = d_in[3];
  const void* bo   = d_in[4];
  int* flagp = (int*)d_ws;
  uint16_t* planes = (uint16_t*)((char*)d_ws + 64);
  uint16_t* y_ws   = planes + 3 * PLANE;
  uint16_t* wqkvT  = y_ws + (size_t)MM * DD;
  uint16_t* woT    = wqkvT + (size_t)NQKV * KK;
  uint16_t* xbf    = y_ws;   // overlay: consumed before attn writes y

  detect_k<<<1, 256, 0, stream>>>((const uint16_t*)x, flagp);
  prep_k<<<1344, 256, 0, stream>>>(x, xbf, Wqkv, wqkvT, Wo, woT, flagp);
  qkv128_k<<<dim3(MM / 128, NQKV / 128), 256, 0, stream>>>(xbf, wqkvT, bqkv, planes, flagp);
  attn_k<<<dim3(32, BB * HH), 256, 0, stream>>>(planes, y_ws);
  out64_k<<<dim3(MM / 128, DD / 64), 256, 0, stream>>>(y_ws, woT, bo, d_out, flagp);
}